// Round 2
// 686.595 us; speedup vs baseline: 1.0372x; 1.0372x over previous
//
#include <hip/hip_runtime.h>
#include <hip/hip_bf16.h>
#include <math.h>

#define N_NODES 50000
#define N_EDGES 800000
#define IN_NODE 256
#define IN_EDGE 64
#define OUT_DIM 128

typedef __attribute__((ext_vector_type(8))) short short8;   // 8 bf16 (4 VGPR)
typedef __attribute__((ext_vector_type(4))) float f32x4;    // MFMA accum

__device__ inline short f2bf(float x) {   // RNE float->bf16 (no NaN inputs here)
    union { float f; unsigned u; } v; v.f = x;
    unsigned r = v.u + 0x7fff + ((v.u >> 16) & 1);
    return (short)(r >> 16);
}

__device__ inline void cvt_store8(short* p, float4 a, float4 b) {
    union { short h[8]; uint4 u; } t;
    t.h[0] = f2bf(a.x); t.h[1] = f2bf(a.y); t.h[2] = f2bf(a.z); t.h[3] = f2bf(a.w);
    t.h[4] = f2bf(b.x); t.h[5] = f2bf(b.y); t.h[6] = f2bf(b.z); t.h[7] = f2bf(b.w);
    *(uint4*)p = t.u;
}

// ---------------------------------------------------------------------------
// K0: v_e = We^T @ Wa_edge (64 floats) so s_e is an exact fp32 dot: fe . v_e
// ---------------------------------------------------------------------------
__global__ void k0_ve(const float* __restrict__ We, const float* __restrict__ Wa,
                      float* __restrict__ v_e)
{
    const int k = threadIdx.x;
    if (k < IN_EDGE) {
        float s = 0.f;
        for (int c = 0; c < IN_EDGE; ++c)
            s += We[c * IN_EDGE + k] * Wa[2 * OUT_DIM + c];
        v_e[k] = s;
    }
}

// ---------------------------------------------------------------------------
// K_deg: degree histogram (before scan so the CSR fill can fuse into k2)
// ---------------------------------------------------------------------------
__global__ __launch_bounds__(256) void k_deg(const int* __restrict__ dst,
                                             int* __restrict__ deg)
{
    const int i = (blockIdx.x * 256 + threadIdx.x) * 4;
    if (i < N_EDGES) {
        const int4 d = *(const int4*)&dst[i];
        atomicAdd(&deg[d.x], 1);
        atomicAdd(&deg[d.y], 1);
        atomicAdd(&deg[d.z], 1);
        atomicAdd(&deg[d.w], 1);
    }
}

// ---------------------------------------------------------------------------
// K1: z = feats_node @ Wn^T (fp32 VALU GEMM — round-0 verified version).
//     Outputs: zb (bf16 z), s_src/s_dst (exact fp32 logit partials).
// ---------------------------------------------------------------------------
#define K1_MT 64
#define K1_KT 32

__global__ __launch_bounds__(256) void k1_node_gemm(
    const float* __restrict__ fn, const float* __restrict__ Wn,
    const float* __restrict__ Wa,
    __hip_bfloat16* __restrict__ zb,
    float* __restrict__ s_src, float* __restrict__ s_dst)
{
    __shared__ float A_s[K1_KT][K1_MT + 4];    // [k][node]
    __shared__ float B_s[K1_KT][OUT_DIM + 4];  // [k][c]
    __shared__ float red_s[K1_MT][17];
    __shared__ float red_d[K1_MT][17];

    const int t  = threadIdx.x;
    const int m0 = blockIdx.x * K1_MT;
    const int tn = t & 15;
    const int tm = t >> 4;
    const int r0 = tm * 4;
    const int c0 = tn * 8;

    float acc[4][8];
    for (int i = 0; i < 4; ++i)
        for (int j = 0; j < 8; ++j) acc[i][j] = 0.f;

    for (int k0 = 0; k0 < IN_NODE; k0 += K1_KT) {
        {
            const int chunk = t & 7;
            const int nd    = t >> 3;
            for (int hh = 0; hh < 2; ++hh) {
                const int node = nd + hh * 32;
                int gr = m0 + node; if (gr >= N_NODES) gr = N_NODES - 1;
                const float4 v = *(const float4*)&fn[(size_t)gr * IN_NODE + k0 + chunk * 4];
                A_s[chunk * 4 + 0][node] = v.x;
                A_s[chunk * 4 + 1][node] = v.y;
                A_s[chunk * 4 + 2][node] = v.z;
                A_s[chunk * 4 + 3][node] = v.w;
            }
        }
        {
            const int chunk = t & 7;
            const int cb    = t >> 3;
            for (int hh = 0; hh < 4; ++hh) {
                const int c = cb + hh * 32;
                const float4 v = *(const float4*)&Wn[(size_t)c * IN_NODE + k0 + chunk * 4];
                B_s[chunk * 4 + 0][c] = v.x;
                B_s[chunk * 4 + 1][c] = v.y;
                B_s[chunk * 4 + 2][c] = v.z;
                B_s[chunk * 4 + 3][c] = v.w;
            }
        }
        __syncthreads();

        for (int k = 0; k < K1_KT; ++k) {
            const float4 a  = *(const float4*)&A_s[k][r0];
            const float4 b0 = *(const float4*)&B_s[k][c0];
            const float4 b1 = *(const float4*)&B_s[k][c0 + 4];
            const float av[4] = {a.x, a.y, a.z, a.w};
            const float bv[8] = {b0.x, b0.y, b0.z, b0.w, b1.x, b1.y, b1.z, b1.w};
            for (int i = 0; i < 4; ++i)
                for (int j = 0; j < 8; ++j)
                    acc[i][j] += av[i] * bv[j];
        }
        __syncthreads();
    }

    float wa_s[8], wa_d[8];
    for (int j = 0; j < 8; ++j) {
        wa_s[j] = Wa[c0 + j];
        wa_d[j] = Wa[OUT_DIM + c0 + j];
    }
    float ps[4], pd[4];
    for (int i = 0; i < 4; ++i) {
        float a = 0.f, b = 0.f;
        for (int j = 0; j < 8; ++j) {
            a += wa_s[j] * acc[i][j];
            b += wa_d[j] * acc[i][j];
        }
        ps[i] = a; pd[i] = b;
    }

    for (int i = 0; i < 4; ++i) {
        const int node = m0 + r0 + i;
        if (node < N_NODES) {
            alignas(16) __hip_bfloat16 tmp[8];
            for (int j = 0; j < 8; ++j) tmp[j] = __float2bfloat16(acc[i][j]);
            *(uint4*)&zb[(size_t)node * OUT_DIM + c0] = *(const uint4*)tmp;
        }
    }

    for (int i = 0; i < 4; ++i) {
        red_s[r0 + i][tn] = ps[i];
        red_d[r0 + i][tn] = pd[i];
    }
    __syncthreads();
    if (t < K1_MT) {
        const int node = m0 + t;
        if (node < N_NODES) {
            float a = 0.f, b = 0.f;
            for (int j = 0; j < 16; ++j) { a += red_s[t][j]; b += red_d[t][j]; }
            s_src[node] = a;
            s_dst[node] = b;
        }
    }
}

// ---------------------------------------------------------------------------
// K2 (MFMA): ze = fe @ We^T (bf16 MFMA, fp32 out — round-0 verified core).
//   s_e computed fp32 during staging, kept in LDS (exact logit path).
//   Fused CSR fill epilogue (verbatim old-k5 logic).
// ---------------------------------------------------------------------------
__global__ __launch_bounds__(256) void k2_edge_gemm_mfma(
    const float* __restrict__ fe, const float* __restrict__ We,
    const float* __restrict__ v_e,
    const int* __restrict__ src, const int* __restrict__ dst,
    const float* __restrict__ s_src, const float* __restrict__ s_dst,
    int* __restrict__ cursor,
    float* __restrict__ ze_out, int* __restrict__ csr_src,
    float* __restrict__ csr_e)
{
    __shared__ alignas(16) short A_lds[128][72];  // [edge][k] bf16, +8 pad
    __shared__ alignas(16) short B_lds[64][72];   // [col][k]  bf16, +8 pad
    __shared__ float se_lds[128];

    const int t    = threadIdx.x;
    const int lane = t & 63;
    const int w    = t >> 6;          // wave 0..3
    const long e0  = (long)blockIdx.x * 128;

    // --- stage A: fe rows -> bf16 LDS, plus fp32 s_e
    {
        const int edge = t >> 1, half = t & 1;
        const float4* rp = (const float4*)&fe[(e0 + edge) * IN_EDGE + half * 32];
        float4 va[8];
        for (int q = 0; q < 8; ++q) va[q] = rp[q];

        float part = 0.f;
        for (int q = 0; q < 8; ++q) {
            const float4 w4 = *(const float4*)&v_e[half * 32 + q * 4];
            part += va[q].x * w4.x + va[q].y * w4.y
                  + va[q].z * w4.z + va[q].w * w4.w;
        }
        const float other = __shfl_xor(part, 1, 64);
        if (half == 0) se_lds[edge] = part + other;

        short* wp = &A_lds[edge][half * 32];
        for (int q = 0; q < 4; ++q)
            cvt_store8(wp + q * 8, va[2 * q], va[2 * q + 1]);
    }
    // --- stage B: We[c][k] -> bf16 LDS
    {
        const int row = t >> 2, kq = (t & 3) * 16;
        const float4* rp = (const float4*)&We[(size_t)row * IN_EDGE + kq];
        cvt_store8(&B_lds[row][kq + 0], rp[0], rp[1]);
        cvt_store8(&B_lds[row][kq + 8], rp[2], rp[3]);
    }
    __syncthreads();

    const int lrow = lane & 15;
    const int lk   = (lane >> 4) * 8;

    f32x4 acc[2][4];
    for (int r = 0; r < 2; ++r)
        for (int c = 0; c < 4; ++c)
            acc[r][c] = (f32x4){0.f, 0.f, 0.f, 0.f};

    for (int s = 0; s < 2; ++s) {
        const int kk = s * 32 + lk;
        short8 aF[2], bF[4];
        for (int r = 0; r < 2; ++r)
            aF[r] = *(const short8*)&A_lds[w * 32 + r * 16 + lrow][kk];
        for (int c = 0; c < 4; ++c)
            bF[c] = *(const short8*)&B_lds[c * 16 + lrow][kk];
        for (int r = 0; r < 2; ++r)
            for (int c = 0; c < 4; ++c)
                acc[r][c] = __builtin_amdgcn_mfma_f32_16x16x32_bf16(
                    aF[r], bF[c], acc[r][c], 0, 0, 0);
    }

    // --- epilogue: write ze (fp32)
    const int rquad = lane >> 4;
    for (int r = 0; r < 2; ++r) {
        for (int c = 0; c < 4; ++c) {
            for (int reg = 0; reg < 4; ++reg) {
                const long row = e0 + w * 32 + r * 16 + rquad * 4 + reg;
                ze_out[row * IN_EDGE + c * 16 + lrow] = acc[r][c][reg];
            }
        }
    }

    // --- fused CSR fill (verbatim old-k5 logic, s_e from LDS)
    if (t < 128) {
        const long e = e0 + t;
        const int d = dst[e];
        const int s = src[e];
        float lg = s_src[s] + s_dst[d] + se_lds[t];
        lg = (lg > 0.f) ? lg : 0.2f * lg;
        const int pos = atomicAdd(&cursor[d], 1);
        csr_src[pos] = s;
        csr_e[pos]   = lg;
    }
}

// ---------------------------------------------------------------------------
// K4: single-block scan -> offsets + cursor
// ---------------------------------------------------------------------------
#define SCAN_T 1024
#define SCAN_C 49

__global__ __launch_bounds__(SCAN_T) void k4_scan(
    const int* __restrict__ deg, int* __restrict__ off, int* __restrict__ cursor)
{
    __shared__ int part[SCAN_T];
    const int t = threadIdx.x;
    const int lo = t * SCAN_C;
    int hi = lo + SCAN_C; if (hi > N_NODES) hi = N_NODES;

    int s = 0;
    for (int i = lo; i < hi; ++i) s += deg[i];
    part[t] = s;
    __syncthreads();
    for (int d = 1; d < SCAN_T; d <<= 1) {
        int v = 0;
        if (t >= d) v = part[t - d];
        __syncthreads();
        if (t >= d) part[t] += v;
        __syncthreads();
    }
    int run = (t == 0) ? 0 : part[t - 1];
    for (int i = lo; i < hi; ++i) {
        off[i] = run; cursor[i] = run;
        run += deg[i];
    }
    if (t == SCAN_T - 1) off[N_NODES] = part[SCAN_T - 1];
}

// ---------------------------------------------------------------------------
// K6: one wave per dst node. Lane-parallel exp per 64-edge chunk; weights
//   redistributed with a UNIFORM __shfl (hoisted out of the divergent guard
//   — source lanes always active). Aggregation: 16 B/lane zb loads, 16 lanes
//   per z-row -> 4 edges per iteration; xor-reduce across edge sub-groups.
// ---------------------------------------------------------------------------
__global__ __launch_bounds__(256) void k6_aggregate(
    const int* __restrict__ off, const int* __restrict__ csr_src,
    const float* __restrict__ csr_e, const __hip_bfloat16* __restrict__ zb,
    float* __restrict__ h)
{
    const int node = (int)((blockIdx.x * blockDim.x + threadIdx.x) >> 6);
    const int lane = threadIdx.x & 63;
    if (node >= N_NODES) return;

    const int beg = off[node];
    const int end = off[node + 1];
    const int deg = end - beg;

    const int cgrp = lane & 15;    // channel group: cols [cgrp*8, cgrp*8+8)
    const int eidx = lane >> 4;    // edge sub-index 0..3

    float out[8] = {0.f, 0.f, 0.f, 0.f, 0.f, 0.f, 0.f, 0.f};

    if (deg > 0) {
        float m = -INFINITY;
        for (int j = lane; j < deg; j += 64) m = fmaxf(m, csr_e[beg + j]);
        for (int o = 32; o > 0; o >>= 1) m = fmaxf(m, __shfl_xor(m, o, 64));

        float l = 0.f;
        for (int c0 = 0; c0 < deg; c0 += 64) {
            const int cl = min(64, deg - c0);
            float wv = 0.f;
            if (lane < cl) wv = __expf(csr_e[beg + c0 + lane] - m);
            float ws = wv;
            for (int o = 32; o > 0; o >>= 1) ws += __shfl_xor(ws, o, 64);
            l += ws;

            for (int jj = 0; jj < cl; jj += 4) {
                const int j  = jj + eidx;
                const int jc = (j < cl) ? j : (cl - 1);   // clamp for uniform shfl
                const float wgt = __shfl(wv, jc, 64);     // uniform control flow
                if (j < cl) {
                    const int s = csr_src[beg + c0 + j];
                    const uint4 zv = *(const uint4*)&zb[(size_t)s * OUT_DIM + cgrp * 8];
                    const unsigned* zu = (const unsigned*)&zv;
                    for (int q = 0; q < 4; ++q) {
                        out[2 * q]     += wgt * __uint_as_float(zu[q] << 16);
                        out[2 * q + 1] += wgt * __uint_as_float(zu[q] & 0xffff0000u);
                    }
                }
            }
        }
        // reduce partials across the 4 edge sub-groups (lanes ^16, ^32)
        for (int i = 0; i < 8; ++i) {
            out[i] += __shfl_xor(out[i], 16, 64);
            out[i] += __shfl_xor(out[i], 32, 64);
        }
        const float inv = 1.f / fmaxf(l, 1e-38f);
        for (int i = 0; i < 8; ++i) out[i] *= inv;
    }

    if (lane < 16) {
        float4 o0 = make_float4(out[0], out[1], out[2], out[3]);
        float4 o1 = make_float4(out[4], out[5], out[6], out[7]);
        float* hp = &h[(size_t)node * OUT_DIM + lane * 8];
        *(float4*)(hp + 0) = o0;
        *(float4*)(hp + 4) = o1;
    }
}

// ---------------------------------------------------------------------------
extern "C" void kernel_launch(void* const* d_in, const int* in_sizes, int n_in,
                              void* d_out, int out_size, void* d_ws, size_t ws_size,
                              hipStream_t stream)
{
    const float* fn  = (const float*)d_in[0];
    const float* fe  = (const float*)d_in[1];
    const int*   src = (const int*)d_in[2];
    const int*   dst = (const int*)d_in[3];
    const float* Wn  = (const float*)d_in[4];
    const float* We  = (const float*)d_in[5];
    const float* Wa  = (const float*)d_in[6];

    float* h_out  = (float*)d_out;                          // [50000,128]
    float* ze_out = h_out + (size_t)N_NODES * OUT_DIM;      // [800000,64]

    char* p = (char*)d_ws;
    auto alloc = [&](size_t bytes) -> char* {
        char* r = p;
        p += (bytes + 255) & ~(size_t)255;
        return r;
    };
    __hip_bfloat16* zb = (__hip_bfloat16*)alloc((size_t)N_NODES * OUT_DIM * 2);
    float* s_src   = (float*)alloc((size_t)N_NODES * 4);
    float* s_dst   = (float*)alloc((size_t)N_NODES * 4);
    int*   deg     = (int*)alloc((size_t)N_NODES * 4);
    int*   off     = (int*)alloc((size_t)(N_NODES + 1) * 4);
    int*   cursor  = (int*)alloc((size_t)N_NODES * 4);
    int*   csr_src = (int*)alloc((size_t)N_EDGES * 4);
    float* csr_e   = (float*)alloc((size_t)N_EDGES * 4);
    float* v_e     = (float*)alloc((size_t)IN_EDGE * 4);

    hipMemsetAsync(deg, 0, (size_t)N_NODES * sizeof(int), stream);

    k0_ve<<<1, 64, 0, stream>>>(We, Wa, v_e);
    k_deg<<<(N_EDGES / 4 + 255) / 256, 256, 0, stream>>>(dst, deg);
    k4_scan<<<1, SCAN_T, 0, stream>>>(deg, off, cursor);
    k1_node_gemm<<<(N_NODES + K1_MT - 1) / K1_MT, 256, 0, stream>>>(
        fn, Wn, Wa, zb, s_src, s_dst);
    k2_edge_gemm_mfma<<<N_EDGES / 128, 256, 0, stream>>>(
        fe, We, v_e, src, dst, s_src, s_dst, cursor, ze_out, csr_src, csr_e);
    k6_aggregate<<<(N_NODES + 3) / 4, 256, 0, stream>>>(
        off, csr_src, csr_e, zb, h_out);
}

// Round 3
// 664.393 us; speedup vs baseline: 1.0718x; 1.0334x over previous
//
#include <hip/hip_runtime.h>
#include <hip/hip_bf16.h>
#include <math.h>

#define N_NODES 50000
#define N_EDGES 800000
#define IN_NODE 256
#define IN_EDGE 64
#define OUT_DIM 128

typedef __attribute__((ext_vector_type(8))) short short8;   // 8 bf16 (4 VGPR)
typedef __attribute__((ext_vector_type(4))) float f32x4;    // MFMA accum

__device__ inline short f2bf(float x) {   // RNE float->bf16 (no NaN inputs here)
    union { float f; unsigned u; } v; v.f = x;
    unsigned r = v.u + 0x7fff + ((v.u >> 16) & 1);
    return (short)(r >> 16);
}

__device__ inline void cvt_store8(short* p, float4 a, float4 b) {
    union { short h[8]; uint4 u; } t;
    t.h[0] = f2bf(a.x); t.h[1] = f2bf(a.y); t.h[2] = f2bf(a.z); t.h[3] = f2bf(a.w);
    t.h[4] = f2bf(b.x); t.h[5] = f2bf(b.y); t.h[6] = f2bf(b.z); t.h[7] = f2bf(b.w);
    *(uint4*)p = t.u;
}

// ---------------------------------------------------------------------------
// K0: precompute logit-projection vectors so all logits are exact fp32 dots:
//   v_e[k]   = sum_c We[c][k] * Wa[2*OUT+c]   (64)  -> s_e   = fe . v_e
//   u_src[k] = sum_c Wn[c][k] * Wa[c]         (256) -> s_src = fn . u_src
//   u_dst[k] = sum_c Wn[c][k] * Wa[OUT+c]     (256) -> s_dst = fn . u_dst
// ---------------------------------------------------------------------------
__global__ __launch_bounds__(256) void k0_prep(
    const float* __restrict__ We, const float* __restrict__ Wn,
    const float* __restrict__ Wa,
    float* __restrict__ v_e, float* __restrict__ u_src, float* __restrict__ u_dst)
{
    const int k = threadIdx.x;
    if (k < IN_EDGE) {
        float s = 0.f;
        for (int c = 0; c < IN_EDGE; ++c)
            s += We[c * IN_EDGE + k] * Wa[2 * OUT_DIM + c];
        v_e[k] = s;
    }
    float a = 0.f, b = 0.f;
    for (int c = 0; c < OUT_DIM; ++c) {
        const float w = Wn[(size_t)c * IN_NODE + k];
        a += Wa[c] * w;
        b += Wa[OUT_DIM + c] * w;
    }
    u_src[k] = a;
    u_dst[k] = b;
}

// ---------------------------------------------------------------------------
// K_deg: degree histogram (before scan so the CSR fill can fuse into k2)
// ---------------------------------------------------------------------------
__global__ __launch_bounds__(256) void k_deg(const int* __restrict__ dst,
                                             int* __restrict__ deg)
{
    const int i = (blockIdx.x * 256 + threadIdx.x) * 4;
    if (i < N_EDGES) {
        const int4 d = *(const int4*)&dst[i];
        atomicAdd(&deg[d.x], 1);
        atomicAdd(&deg[d.y], 1);
        atomicAdd(&deg[d.z], 1);
        atomicAdd(&deg[d.w], 1);
    }
}

// ---------------------------------------------------------------------------
// K1 (MFMA): z = fn @ Wn^T via bf16 16x16x32 MFMA (same fragment pattern as
//   the verified k2). zb output is bf16 anyway; input rounding adds ~2x the
//   existing output-quantization error — within threshold.
//   Exact fp32 logit partials s_src/s_dst computed during staging from u_*.
//   Tile: 128 nodes x 128 cols, BK=64, 4 waves, acc[2][8] per wave.
// ---------------------------------------------------------------------------
#define K1_BK 64

__global__ __launch_bounds__(256) void k1_node_mfma(
    const float* __restrict__ fn, const float* __restrict__ Wn,
    const float* __restrict__ u_src, const float* __restrict__ u_dst,
    __hip_bfloat16* __restrict__ zb,
    float* __restrict__ s_src, float* __restrict__ s_dst)
{
    __shared__ alignas(16) short A_lds[128][72];   // [node][k] bf16, +8 pad
    __shared__ alignas(16) short B_lds[128][72];   // [col][k]  bf16, +8 pad

    const int t    = threadIdx.x;
    const int lane = t & 63;
    const int w    = t >> 6;
    const int m0   = blockIdx.x * 128;

    const int nd   = t >> 1;      // node-in-tile / Wn row (0..127)
    const int half = t & 1;       // k-half within BK chunk

    int grow = m0 + nd; if (grow >= N_NODES) grow = N_NODES - 1;
    const float* arow = &fn[(size_t)grow * IN_NODE];
    const float* brow = &Wn[(size_t)nd * IN_NODE];

    float sa = 0.f, sb = 0.f;

    const int lrow = lane & 15;
    const int lk   = (lane >> 4) * 8;

    f32x4 acc[2][8];
    for (int r = 0; r < 2; ++r)
        for (int c = 0; c < 8; ++c)
            acc[r][c] = (f32x4){0.f, 0.f, 0.f, 0.f};

    for (int k0 = 0; k0 < IN_NODE; k0 += K1_BK) {
        // stage A (fn rows) + fp32 logit partials
        {
            const float4* rp = (const float4*)&arow[k0 + half * 32];
            float4 va[8];
            for (int q = 0; q < 8; ++q) va[q] = rp[q];
            for (int q = 0; q < 8; ++q) {
                const float4 us = *(const float4*)&u_src[k0 + half * 32 + q * 4];
                const float4 ud = *(const float4*)&u_dst[k0 + half * 32 + q * 4];
                sa += va[q].x * us.x + va[q].y * us.y + va[q].z * us.z + va[q].w * us.w;
                sb += va[q].x * ud.x + va[q].y * ud.y + va[q].z * ud.z + va[q].w * ud.w;
            }
            short* wp = &A_lds[nd][half * 32];
            for (int q = 0; q < 4; ++q)
                cvt_store8(wp + q * 8, va[2 * q], va[2 * q + 1]);
        }
        // stage B (Wn rows = z columns)
        {
            const float4* rp = (const float4*)&brow[k0 + half * 32];
            float4 vb[8];
            for (int q = 0; q < 8; ++q) vb[q] = rp[q];
            short* wp = &B_lds[nd][half * 32];
            for (int q = 0; q < 4; ++q)
                cvt_store8(wp + q * 8, vb[2 * q], vb[2 * q + 1]);
        }
        __syncthreads();

        for (int s = 0; s < 2; ++s) {     // two 32-k steps per chunk
            const int kk = s * 32 + lk;
            short8 aF[2], bF[8];
            for (int r = 0; r < 2; ++r)
                aF[r] = *(const short8*)&A_lds[w * 32 + r * 16 + lrow][kk];
            for (int c = 0; c < 8; ++c)
                bF[c] = *(const short8*)&B_lds[c * 16 + lrow][kk];
            for (int r = 0; r < 2; ++r)
                for (int c = 0; c < 8; ++c)
                    acc[r][c] = __builtin_amdgcn_mfma_f32_16x16x32_bf16(
                        aF[r], bF[c], acc[r][c], 0, 0, 0);
        }
        __syncthreads();
    }

    // exact fp32 logit partials: combine thread-pair halves (intra-wave)
    {
        const float oa = __shfl_xor(sa, 1, 64);
        const float ob = __shfl_xor(sb, 1, 64);
        if (half == 0 && (m0 + nd) < N_NODES) {
            s_src[m0 + nd] = sa + oa;
            s_dst[m0 + nd] = sb + ob;
        }
    }

    // epilogue: zb bf16 (C/D layout: col = lane&15, row = (lane>>4)*4 + reg)
    const int rq = lane >> 4;
    for (int r = 0; r < 2; ++r) {
        for (int reg = 0; reg < 4; ++reg) {
            const int row = m0 + w * 32 + r * 16 + rq * 4 + reg;
            if (row < N_NODES) {
                for (int c = 0; c < 8; ++c)
                    zb[(size_t)row * OUT_DIM + c * 16 + lrow] =
                        __float2bfloat16(acc[r][c][reg]);
            }
        }
    }
}

// ---------------------------------------------------------------------------
// K2 (MFMA): ze = fe @ We^T (bf16 MFMA, fp32 out — verified core).
//   s_e computed fp32 during staging, kept in LDS (exact logit path).
//   Fused CSR fill epilogue (verified round-2 version).
// ---------------------------------------------------------------------------
__global__ __launch_bounds__(256) void k2_edge_gemm_mfma(
    const float* __restrict__ fe, const float* __restrict__ We,
    const float* __restrict__ v_e,
    const int* __restrict__ src, const int* __restrict__ dst,
    const float* __restrict__ s_src, const float* __restrict__ s_dst,
    int* __restrict__ cursor,
    float* __restrict__ ze_out, int* __restrict__ csr_src,
    float* __restrict__ csr_e)
{
    __shared__ alignas(16) short A_lds[128][72];  // [edge][k] bf16, +8 pad
    __shared__ alignas(16) short B_lds[64][72];   // [col][k]  bf16, +8 pad
    __shared__ float se_lds[128];

    const int t    = threadIdx.x;
    const int lane = t & 63;
    const int w    = t >> 6;          // wave 0..3
    const long e0  = (long)blockIdx.x * 128;

    // --- stage A: fe rows -> bf16 LDS, plus fp32 s_e
    {
        const int edge = t >> 1, half = t & 1;
        const float4* rp = (const float4*)&fe[(e0 + edge) * IN_EDGE + half * 32];
        float4 va[8];
        for (int q = 0; q < 8; ++q) va[q] = rp[q];

        float part = 0.f;
        for (int q = 0; q < 8; ++q) {
            const float4 w4 = *(const float4*)&v_e[half * 32 + q * 4];
            part += va[q].x * w4.x + va[q].y * w4.y
                  + va[q].z * w4.z + va[q].w * w4.w;
        }
        const float other = __shfl_xor(part, 1, 64);
        if (half == 0) se_lds[edge] = part + other;

        short* wp = &A_lds[edge][half * 32];
        for (int q = 0; q < 4; ++q)
            cvt_store8(wp + q * 8, va[2 * q], va[2 * q + 1]);
    }
    // --- stage B: We[c][k] -> bf16 LDS
    {
        const int row = t >> 2, kq = (t & 3) * 16;
        const float4* rp = (const float4*)&We[(size_t)row * IN_EDGE + kq];
        cvt_store8(&B_lds[row][kq + 0], rp[0], rp[1]);
        cvt_store8(&B_lds[row][kq + 8], rp[2], rp[3]);
    }
    __syncthreads();

    const int lrow = lane & 15;
    const int lk   = (lane >> 4) * 8;

    f32x4 acc[2][4];
    for (int r = 0; r < 2; ++r)
        for (int c = 0; c < 4; ++c)
            acc[r][c] = (f32x4){0.f, 0.f, 0.f, 0.f};

    for (int s = 0; s < 2; ++s) {
        const int kk = s * 32 + lk;
        short8 aF[2], bF[4];
        for (int r = 0; r < 2; ++r)
            aF[r] = *(const short8*)&A_lds[w * 32 + r * 16 + lrow][kk];
        for (int c = 0; c < 4; ++c)
            bF[c] = *(const short8*)&B_lds[c * 16 + lrow][kk];
        for (int r = 0; r < 2; ++r)
            for (int c = 0; c < 4; ++c)
                acc[r][c] = __builtin_amdgcn_mfma_f32_16x16x32_bf16(
                    aF[r], bF[c], acc[r][c], 0, 0, 0);
    }

    // --- epilogue: write ze (fp32)
    const int rquad = lane >> 4;
    for (int r = 0; r < 2; ++r) {
        for (int c = 0; c < 4; ++c) {
            for (int reg = 0; reg < 4; ++reg) {
                const long row = e0 + w * 32 + r * 16 + rquad * 4 + reg;
                ze_out[row * IN_EDGE + c * 16 + lrow] = acc[r][c][reg];
            }
        }
    }

    // --- fused CSR fill (verified logic, s_e from LDS)
    if (t < 128) {
        const long e = e0 + t;
        const int d = dst[e];
        const int s = src[e];
        float lg = s_src[s] + s_dst[d] + se_lds[t];
        lg = (lg > 0.f) ? lg : 0.2f * lg;
        const int pos = atomicAdd(&cursor[d], 1);
        csr_src[pos] = s;
        csr_e[pos]   = lg;
    }
}

// ---------------------------------------------------------------------------
// K4: single-block scan -> offsets + cursor
// ---------------------------------------------------------------------------
#define SCAN_T 1024
#define SCAN_C 49

__global__ __launch_bounds__(SCAN_T) void k4_scan(
    const int* __restrict__ deg, int* __restrict__ off, int* __restrict__ cursor)
{
    __shared__ int part[SCAN_T];
    const int t = threadIdx.x;
    const int lo = t * SCAN_C;
    int hi = lo + SCAN_C; if (hi > N_NODES) hi = N_NODES;

    int s = 0;
    for (int i = lo; i < hi; ++i) s += deg[i];
    part[t] = s;
    __syncthreads();
    for (int d = 1; d < SCAN_T; d <<= 1) {
        int v = 0;
        if (t >= d) v = part[t - d];
        __syncthreads();
        if (t >= d) part[t] += v;
        __syncthreads();
    }
    int run = (t == 0) ? 0 : part[t - 1];
    for (int i = lo; i < hi; ++i) {
        off[i] = run; cursor[i] = run;
        run += deg[i];
    }
    if (t == SCAN_T - 1) off[N_NODES] = part[SCAN_T - 1];
}

// ---------------------------------------------------------------------------
// K6: one wave per dst node (verified round-2 version).
// ---------------------------------------------------------------------------
__global__ __launch_bounds__(256) void k6_aggregate(
    const int* __restrict__ off, const int* __restrict__ csr_src,
    const float* __restrict__ csr_e, const __hip_bfloat16* __restrict__ zb,
    float* __restrict__ h)
{
    const int node = (int)((blockIdx.x * blockDim.x + threadIdx.x) >> 6);
    const int lane = threadIdx.x & 63;
    if (node >= N_NODES) return;

    const int beg = off[node];
    const int end = off[node + 1];
    const int deg = end - beg;

    const int cgrp = lane & 15;    // channel group: cols [cgrp*8, cgrp*8+8)
    const int eidx = lane >> 4;    // edge sub-index 0..3

    float out[8] = {0.f, 0.f, 0.f, 0.f, 0.f, 0.f, 0.f, 0.f};

    if (deg > 0) {
        float m = -INFINITY;
        for (int j = lane; j < deg; j += 64) m = fmaxf(m, csr_e[beg + j]);
        for (int o = 32; o > 0; o >>= 1) m = fmaxf(m, __shfl_xor(m, o, 64));

        float l = 0.f;
        for (int c0 = 0; c0 < deg; c0 += 64) {
            const int cl = min(64, deg - c0);
            float wv = 0.f;
            if (lane < cl) wv = __expf(csr_e[beg + c0 + lane] - m);
            float ws = wv;
            for (int o = 32; o > 0; o >>= 1) ws += __shfl_xor(ws, o, 64);
            l += ws;

            for (int jj = 0; jj < cl; jj += 4) {
                const int j  = jj + eidx;
                const int jc = (j < cl) ? j : (cl - 1);   // clamp for uniform shfl
                const float wgt = __shfl(wv, jc, 64);     // uniform control flow
                if (j < cl) {
                    const int s = csr_src[beg + c0 + j];
                    const uint4 zv = *(const uint4*)&zb[(size_t)s * OUT_DIM + cgrp * 8];
                    const unsigned* zu = (const unsigned*)&zv;
                    for (int q = 0; q < 4; ++q) {
                        out[2 * q]     += wgt * __uint_as_float(zu[q] << 16);
                        out[2 * q + 1] += wgt * __uint_as_float(zu[q] & 0xffff0000u);
                    }
                }
            }
        }
        // reduce partials across the 4 edge sub-groups (lanes ^16, ^32)
        for (int i = 0; i < 8; ++i) {
            out[i] += __shfl_xor(out[i], 16, 64);
            out[i] += __shfl_xor(out[i], 32, 64);
        }
        const float inv = 1.f / fmaxf(l, 1e-38f);
        for (int i = 0; i < 8; ++i) out[i] *= inv;
    }

    if (lane < 16) {
        float4 o0 = make_float4(out[0], out[1], out[2], out[3]);
        float4 o1 = make_float4(out[4], out[5], out[6], out[7]);
        float* hp = &h[(size_t)node * OUT_DIM + lane * 8];
        *(float4*)(hp + 0) = o0;
        *(float4*)(hp + 4) = o1;
    }
}

// ---------------------------------------------------------------------------
extern "C" void kernel_launch(void* const* d_in, const int* in_sizes, int n_in,
                              void* d_out, int out_size, void* d_ws, size_t ws_size,
                              hipStream_t stream)
{
    const float* fn  = (const float*)d_in[0];
    const float* fe  = (const float*)d_in[1];
    const int*   src = (const int*)d_in[2];
    const int*   dst = (const int*)d_in[3];
    const float* Wn  = (const float*)d_in[4];
    const float* We  = (const float*)d_in[5];
    const float* Wa  = (const float*)d_in[6];

    float* h_out  = (float*)d_out;                          // [50000,128]
    float* ze_out = h_out + (size_t)N_NODES * OUT_DIM;      // [800000,64]

    char* p = (char*)d_ws;
    auto alloc = [&](size_t bytes) -> char* {
        char* r = p;
        p += (bytes + 255) & ~(size_t)255;
        return r;
    };
    __hip_bfloat16* zb = (__hip_bfloat16*)alloc((size_t)N_NODES * OUT_DIM * 2);
    float* s_src   = (float*)alloc((size_t)N_NODES * 4);
    float* s_dst   = (float*)alloc((size_t)N_NODES * 4);
    int*   deg     = (int*)alloc((size_t)N_NODES * 4);
    int*   off     = (int*)alloc((size_t)(N_NODES + 1) * 4);
    int*   cursor  = (int*)alloc((size_t)N_NODES * 4);
    int*   csr_src = (int*)alloc((size_t)N_EDGES * 4);
    float* csr_e   = (float*)alloc((size_t)N_EDGES * 4);
    float* v_e     = (float*)alloc((size_t)IN_EDGE * 4);
    float* u_src   = (float*)alloc((size_t)IN_NODE * 4);
    float* u_dst   = (float*)alloc((size_t)IN_NODE * 4);

    hipMemsetAsync(deg, 0, (size_t)N_NODES * sizeof(int), stream);

    k0_prep<<<1, 256, 0, stream>>>(We, Wn, Wa, v_e, u_src, u_dst);
    k_deg<<<(N_EDGES / 4 + 255) / 256, 256, 0, stream>>>(dst, deg);
    k4_scan<<<1, SCAN_T, 0, stream>>>(deg, off, cursor);
    k1_node_mfma<<<(N_NODES + 127) / 128, 256, 0, stream>>>(
        fn, Wn, u_src, u_dst, zb, s_src, s_dst);
    k2_edge_gemm_mfma<<<N_EDGES / 128, 256, 0, stream>>>(
        fe, We, v_e, src, dst, s_src, s_dst, cursor, ze_out, csr_src, csr_e);
    k6_aggregate<<<(N_NODES + 3) / 4, 256, 0, stream>>>(
        off, csr_src, csr_e, zb, h_out);
}

// Round 5
// 648.313 us; speedup vs baseline: 1.0984x; 1.0248x over previous
//
#include <hip/hip_runtime.h>
#include <hip/hip_bf16.h>
#include <math.h>

#define N_NODES 50000
#define N_EDGES 800000
#define IN_NODE 256
#define IN_EDGE 64
#define OUT_DIM 128

typedef __attribute__((ext_vector_type(8))) short short8;   // 8 bf16 (4 VGPR)
typedef __attribute__((ext_vector_type(4))) float f32x4;    // MFMA accum / nt stores

__device__ inline short f2bf(float x) {   // RNE float->bf16 (no NaN inputs here)
    union { float f; unsigned u; } v; v.f = x;
    unsigned r = v.u + 0x7fff + ((v.u >> 16) & 1);
    return (short)(r >> 16);
}

__device__ inline void cvt_store8(short* p, float4 a, float4 b) {
    union { short h[8]; uint4 u; } t;
    t.h[0] = f2bf(a.x); t.h[1] = f2bf(a.y); t.h[2] = f2bf(a.z); t.h[3] = f2bf(a.w);
    t.h[4] = f2bf(b.x); t.h[5] = f2bf(b.y); t.h[6] = f2bf(b.z); t.h[7] = f2bf(b.w);
    *(uint4*)p = t.u;
}

// ---------------------------------------------------------------------------
// K_deg_prep: degree histogram; block 0 additionally computes the logit
// projection vectors (former k0):
//   v_e[k]   = sum_c We[c][k] * Wa[2*OUT+c]   (64)  -> s_e   = fe . v_e
//   u_src[k] = sum_c Wn[c][k] * Wa[c]         (256) -> s_src = fn . u_src
//   u_dst[k] = sum_c Wn[c][k] * Wa[OUT+c]     (256) -> s_dst = fn . u_dst
// ---------------------------------------------------------------------------
__global__ __launch_bounds__(256) void k_deg_prep(
    const int* __restrict__ dst, int* __restrict__ deg,
    const float* __restrict__ We, const float* __restrict__ Wn,
    const float* __restrict__ Wa,
    float* __restrict__ v_e, float* __restrict__ u_src, float* __restrict__ u_dst)
{
    const int i = (blockIdx.x * 256 + threadIdx.x) * 4;
    if (i < N_EDGES) {
        const int4 d = *(const int4*)&dst[i];
        atomicAdd(&deg[d.x], 1);
        atomicAdd(&deg[d.y], 1);
        atomicAdd(&deg[d.z], 1);
        atomicAdd(&deg[d.w], 1);
    }
    if (blockIdx.x == 0) {
        const int k = threadIdx.x;
        if (k < IN_EDGE) {
            float s = 0.f;
            for (int c = 0; c < IN_EDGE; ++c)
                s += We[c * IN_EDGE + k] * Wa[2 * OUT_DIM + c];
            v_e[k] = s;
        }
        float a = 0.f, b = 0.f;
        for (int c = 0; c < OUT_DIM; ++c) {
            const float w = Wn[(size_t)c * IN_NODE + k];
            a += Wa[c] * w;
            b += Wa[OUT_DIM + c] * w;
        }
        u_src[k] = a;
        u_dst[k] = b;
    }
}

// ---------------------------------------------------------------------------
// K1 (MFMA): z = fn @ Wn^T via bf16 16x16x32 MFMA (verified round-3 version).
//   Exact fp32 logit partials s_src/s_dst computed during staging from u_*.
// ---------------------------------------------------------------------------
#define K1_BK 64

__global__ __launch_bounds__(256) void k1_node_mfma(
    const float* __restrict__ fn, const float* __restrict__ Wn,
    const float* __restrict__ u_src, const float* __restrict__ u_dst,
    __hip_bfloat16* __restrict__ zb,
    float* __restrict__ s_src, float* __restrict__ s_dst)
{
    __shared__ alignas(16) short A_lds[128][72];   // [node][k] bf16, +8 pad
    __shared__ alignas(16) short B_lds[128][72];   // [col][k]  bf16, +8 pad

    const int t    = threadIdx.x;
    const int lane = t & 63;
    const int w    = t >> 6;
    const int m0   = blockIdx.x * 128;

    const int nd   = t >> 1;      // node-in-tile / Wn row (0..127)
    const int half = t & 1;       // k-half within BK chunk

    int grow = m0 + nd; if (grow >= N_NODES) grow = N_NODES - 1;
    const float* arow = &fn[(size_t)grow * IN_NODE];
    const float* brow = &Wn[(size_t)nd * IN_NODE];

    float sa = 0.f, sb = 0.f;

    const int lrow = lane & 15;
    const int lk   = (lane >> 4) * 8;

    f32x4 acc[2][8];
    for (int r = 0; r < 2; ++r)
        for (int c = 0; c < 8; ++c)
            acc[r][c] = (f32x4){0.f, 0.f, 0.f, 0.f};

    for (int k0 = 0; k0 < IN_NODE; k0 += K1_BK) {
        // stage A (fn rows) + fp32 logit partials
        {
            const float4* rp = (const float4*)&arow[k0 + half * 32];
            float4 va[8];
            for (int q = 0; q < 8; ++q) va[q] = rp[q];
            for (int q = 0; q < 8; ++q) {
                const float4 us = *(const float4*)&u_src[k0 + half * 32 + q * 4];
                const float4 ud = *(const float4*)&u_dst[k0 + half * 32 + q * 4];
                sa += va[q].x * us.x + va[q].y * us.y + va[q].z * us.z + va[q].w * us.w;
                sb += va[q].x * ud.x + va[q].y * ud.y + va[q].z * ud.z + va[q].w * ud.w;
            }
            short* wp = &A_lds[nd][half * 32];
            for (int q = 0; q < 4; ++q)
                cvt_store8(wp + q * 8, va[2 * q], va[2 * q + 1]);
        }
        // stage B (Wn rows = z columns)
        {
            const float4* rp = (const float4*)&brow[k0 + half * 32];
            float4 vb[8];
            for (int q = 0; q < 8; ++q) vb[q] = rp[q];
            short* wp = &B_lds[nd][half * 32];
            for (int q = 0; q < 4; ++q)
                cvt_store8(wp + q * 8, vb[2 * q], vb[2 * q + 1]);
        }
        __syncthreads();

        for (int s = 0; s < 2; ++s) {     // two 32-k steps per chunk
            const int kk = s * 32 + lk;
            short8 aF[2], bF[8];
            for (int r = 0; r < 2; ++r)
                aF[r] = *(const short8*)&A_lds[w * 32 + r * 16 + lrow][kk];
            for (int c = 0; c < 8; ++c)
                bF[c] = *(const short8*)&B_lds[c * 16 + lrow][kk];
            for (int r = 0; r < 2; ++r)
                for (int c = 0; c < 8; ++c)
                    acc[r][c] = __builtin_amdgcn_mfma_f32_16x16x32_bf16(
                        aF[r], bF[c], acc[r][c], 0, 0, 0);
        }
        __syncthreads();
    }

    // exact fp32 logit partials: combine thread-pair halves (intra-wave)
    {
        const float oa = __shfl_xor(sa, 1, 64);
        const float ob = __shfl_xor(sb, 1, 64);
        if (half == 0 && (m0 + nd) < N_NODES) {
            s_src[m0 + nd] = sa + oa;
            s_dst[m0 + nd] = sb + ob;
        }
    }

    // epilogue: zb bf16 (C/D layout: col = lane&15, row = (lane>>4)*4 + reg)
    const int rq = lane >> 4;
    for (int r = 0; r < 2; ++r) {
        for (int reg = 0; reg < 4; ++reg) {
            const int row = m0 + w * 32 + r * 16 + rq * 4 + reg;
            if (row < N_NODES) {
                for (int c = 0; c < 8; ++c)
                    zb[(size_t)row * OUT_DIM + c * 16 + lrow] =
                        __float2bfloat16(acc[r][c][reg]);
            }
        }
    }
}

// ---------------------------------------------------------------------------
// K2 (MFMA): ze = fe @ We^T (bf16 MFMA, fp32 out). s_e fp32 during staging
//   (exact logit path). Fused CSR fill right after staging barrier.
//   Epilogue transposes acc through LDS (reusing the A-tile region, free
//   after MFMA) and writes ze with contiguous nontemporal dwordx4 —
//   32 wave-stores/block of 1 KB each instead of 128 4-line scattered ones.
// ---------------------------------------------------------------------------
__global__ __launch_bounds__(256) void k2_edge_gemm_mfma(
    const float* __restrict__ fe, const float* __restrict__ We,
    const float* __restrict__ v_e,
    const int* __restrict__ src, const int* __restrict__ dst,
    const float* __restrict__ s_src, const float* __restrict__ s_dst,
    int* __restrict__ cursor,
    float* __restrict__ ze_out, int* __restrict__ csr_src,
    float* __restrict__ csr_e)
{
    __shared__ alignas(16) short A_lds[128][72];  // [edge][k] bf16, +8 pad
    __shared__ alignas(16) short B_lds[64][72];   // [col][k]  bf16, +8 pad
    __shared__ float se_lds[128];

    // transpose scratch overlays A_lds ONLY (64*68*4 = 17408 B <= 18432 B);
    // B_lds and se_lds are untouched by it.
    float (*zt)[68] = reinterpret_cast<float(*)[68]>(&A_lds[0][0]);

    const int t    = threadIdx.x;
    const int lane = t & 63;
    const int w    = t >> 6;          // wave 0..3
    const long e0  = (long)blockIdx.x * 128;

    // --- stage A: fe rows -> bf16 LDS, plus fp32 s_e
    {
        const int edge = t >> 1, half = t & 1;
        const float4* rp = (const float4*)&fe[(e0 + edge) * IN_EDGE + half * 32];
        float4 va[8];
        for (int q = 0; q < 8; ++q) va[q] = rp[q];

        float part = 0.f;
        for (int q = 0; q < 8; ++q) {
            const float4 w4 = *(const float4*)&v_e[half * 32 + q * 4];
            part += va[q].x * w4.x + va[q].y * w4.y
                  + va[q].z * w4.z + va[q].w * w4.w;
        }
        const float other = __shfl_xor(part, 1, 64);
        if (half == 0) se_lds[edge] = part + other;

        short* wp = &A_lds[edge][half * 32];
        for (int q = 0; q < 4; ++q)
            cvt_store8(wp + q * 8, va[2 * q], va[2 * q + 1]);
    }
    // --- stage B: We[c][k] -> bf16 LDS
    {
        const int row = t >> 2, kq = (t & 3) * 16;
        const float4* rp = (const float4*)&We[(size_t)row * IN_EDGE + kq];
        cvt_store8(&B_lds[row][kq + 0], rp[0], rp[1]);
        cvt_store8(&B_lds[row][kq + 8], rp[2], rp[3]);
    }
    __syncthreads();

    // --- fused CSR fill (reads se_lds + globals; overlaps with MFMA below)
    if (t < 128) {
        const long e = e0 + t;
        const int d = dst[e];
        const int s = src[e];
        float lg = s_src[s] + s_dst[d] + se_lds[t];
        lg = (lg > 0.f) ? lg : 0.2f * lg;
        const int pos = atomicAdd(&cursor[d], 1);
        csr_src[pos] = s;
        csr_e[pos]   = lg;
    }

    const int lrow = lane & 15;
    const int lk   = (lane >> 4) * 8;

    f32x4 acc[2][4];
    for (int r = 0; r < 2; ++r)
        for (int c = 0; c < 4; ++c)
            acc[r][c] = (f32x4){0.f, 0.f, 0.f, 0.f};

    for (int s = 0; s < 2; ++s) {
        const int kk = s * 32 + lk;
        short8 aF[2], bF[4];
        for (int r = 0; r < 2; ++r)
            aF[r] = *(const short8*)&A_lds[w * 32 + r * 16 + lrow][kk];
        for (int c = 0; c < 4; ++c)
            bF[c] = *(const short8*)&B_lds[c * 16 + lrow][kk];
        for (int r = 0; r < 2; ++r)
            for (int c = 0; c < 4; ++c)
                acc[r][c] = __builtin_amdgcn_mfma_f32_16x16x32_bf16(
                    aF[r], bF[c], acc[r][c], 0, 0, 0);
    }

    // --- epilogue: two half-tile passes through LDS, contiguous nt stores.
    //     acc value at tile-row R = w*32 + r*16 + rquad*4 + reg,
    //                  col      C = c*16 + lrow.
    const int rquad = lane >> 4;
    for (int p = 0; p < 2; ++p) {
        __syncthreads();               // A-region reads (MFMA / prev pass) done
        if ((w >> 1) == p) {           // pass 0: waves 0,1; pass 1: waves 2,3
            const int rb = w * 32 - p * 64;    // 0 or 32
            for (int r = 0; r < 2; ++r)
                for (int c = 0; c < 4; ++c)
                    for (int reg = 0; reg < 4; ++reg)
                        zt[rb + r * 16 + rquad * 4 + reg][c * 16 + lrow] =
                            acc[r][c][reg];
        }
        __syncthreads();
        for (int it = 0; it < 4; ++it) {
            const int idx = it * 256 + t;      // 0..1023
            const int row = idx >> 4;          // 0..63
            const int c4  = idx & 15;
            const f32x4 v = *(const f32x4*)&zt[row][c4 * 4];
            __builtin_nontemporal_store(
                v, (f32x4*)&ze_out[(e0 + p * 64 + row) * IN_EDGE + c4 * 4]);
        }
    }
}

// ---------------------------------------------------------------------------
// K4: single-block scan -> offsets + cursor
// ---------------------------------------------------------------------------
#define SCAN_T 1024
#define SCAN_C 49

__global__ __launch_bounds__(SCAN_T) void k4_scan(
    const int* __restrict__ deg, int* __restrict__ off, int* __restrict__ cursor)
{
    __shared__ int part[SCAN_T];
    const int t = threadIdx.x;
    const int lo = t * SCAN_C;
    int hi = lo + SCAN_C; if (hi > N_NODES) hi = N_NODES;

    int s = 0;
    for (int i = lo; i < hi; ++i) s += deg[i];
    part[t] = s;
    __syncthreads();
    for (int d = 1; d < SCAN_T; d <<= 1) {
        int v = 0;
        if (t >= d) v = part[t - d];
        __syncthreads();
        if (t >= d) part[t] += v;
        __syncthreads();
    }
    int run = (t == 0) ? 0 : part[t - 1];
    for (int i = lo; i < hi; ++i) {
        off[i] = run; cursor[i] = run;
        run += deg[i];
    }
    if (t == SCAN_T - 1) off[N_NODES] = part[SCAN_T - 1];
}

// ---------------------------------------------------------------------------
// K6: one wave per dst node (verified round-2 version).
// ---------------------------------------------------------------------------
__global__ __launch_bounds__(256) void k6_aggregate(
    const int* __restrict__ off, const int* __restrict__ csr_src,
    const float* __restrict__ csr_e, const __hip_bfloat16* __restrict__ zb,
    float* __restrict__ h)
{
    const int node = (int)((blockIdx.x * blockDim.x + threadIdx.x) >> 6);
    const int lane = threadIdx.x & 63;
    if (node >= N_NODES) return;

    const int beg = off[node];
    const int end = off[node + 1];
    const int deg = end - beg;

    const int cgrp = lane & 15;    // channel group: cols [cgrp*8, cgrp*8+8)
    const int eidx = lane >> 4;    // edge sub-index 0..3

    float out[8] = {0.f, 0.f, 0.f, 0.f, 0.f, 0.f, 0.f, 0.f};

    if (deg > 0) {
        float m = -INFINITY;
        for (int j = lane; j < deg; j += 64) m = fmaxf(m, csr_e[beg + j]);
        for (int o = 32; o > 0; o >>= 1) m = fmaxf(m, __shfl_xor(m, o, 64));

        float l = 0.f;
        for (int c0 = 0; c0 < deg; c0 += 64) {
            const int cl = min(64, deg - c0);
            float wv = 0.f;
            if (lane < cl) wv = __expf(csr_e[beg + c0 + lane] - m);
            float ws = wv;
            for (int o = 32; o > 0; o >>= 1) ws += __shfl_xor(ws, o, 64);
            l += ws;

            for (int jj = 0; jj < cl; jj += 4) {
                const int j  = jj + eidx;
                const int jc = (j < cl) ? j : (cl - 1);   // clamp for uniform shfl
                const float wgt = __shfl(wv, jc, 64);     // uniform control flow
                if (j < cl) {
                    const int s = csr_src[beg + c0 + j];
                    const uint4 zv = *(const uint4*)&zb[(size_t)s * OUT_DIM + cgrp * 8];
                    const unsigned* zu = (const unsigned*)&zv;
                    for (int q = 0; q < 4; ++q) {
                        out[2 * q]     += wgt * __uint_as_float(zu[q] << 16);
                        out[2 * q + 1] += wgt * __uint_as_float(zu[q] & 0xffff0000u);
                    }
                }
            }
        }
        // reduce partials across the 4 edge sub-groups (lanes ^16, ^32)
        for (int i = 0; i < 8; ++i) {
            out[i] += __shfl_xor(out[i], 16, 64);
            out[i] += __shfl_xor(out[i], 32, 64);
        }
        const float inv = 1.f / fmaxf(l, 1e-38f);
        for (int i = 0; i < 8; ++i) out[i] *= inv;
    }

    if (lane < 16) {
        float4 o0 = make_float4(out[0], out[1], out[2], out[3]);
        float4 o1 = make_float4(out[4], out[5], out[6], out[7]);
        float* hp = &h[(size_t)node * OUT_DIM + lane * 8];
        *(float4*)(hp + 0) = o0;
        *(float4*)(hp + 4) = o1;
    }
}

// ---------------------------------------------------------------------------
extern "C" void kernel_launch(void* const* d_in, const int* in_sizes, int n_in,
                              void* d_out, int out_size, void* d_ws, size_t ws_size,
                              hipStream_t stream)
{
    const float* fn  = (const float*)d_in[0];
    const float* fe  = (const float*)d_in[1];
    const int*   src = (const int*)d_in[2];
    const int*   dst = (const int*)d_in[3];
    const float* Wn  = (const float*)d_in[4];
    const float* We  = (const float*)d_in[5];
    const float* Wa  = (const float*)d_in[6];

    float* h_out  = (float*)d_out;                          // [50000,128]
    float* ze_out = h_out + (size_t)N_NODES * OUT_DIM;      // [800000,64]

    char* p = (char*)d_ws;
    auto alloc = [&](size_t bytes) -> char* {
        char* r = p;
        p += (bytes + 255) & ~(size_t)255;
        return r;
    };
    __hip_bfloat16* zb = (__hip_bfloat16*)alloc((size_t)N_NODES * OUT_DIM * 2);
    float* s_src   = (float*)alloc((size_t)N_NODES * 4);
    float* s_dst   = (float*)alloc((size_t)N_NODES * 4);
    int*   deg     = (int*)alloc((size_t)N_NODES * 4);
    int*   off     = (int*)alloc((size_t)(N_NODES + 1) * 4);
    int*   cursor  = (int*)alloc((size_t)N_NODES * 4);
    int*   csr_src = (int*)alloc((size_t)N_EDGES * 4);
    float* csr_e   = (float*)alloc((size_t)N_EDGES * 4);
    float* v_e     = (float*)alloc((size_t)IN_EDGE * 4);
    float* u_src   = (float*)alloc((size_t)IN_NODE * 4);
    float* u_dst   = (float*)alloc((size_t)IN_NODE * 4);

    hipMemsetAsync(deg, 0, (size_t)N_NODES * sizeof(int), stream);

    k_deg_prep<<<(N_EDGES / 4 + 255) / 256, 256, 0, stream>>>(
        dst, deg, We, Wn, Wa, v_e, u_src, u_dst);
    k4_scan<<<1, SCAN_T, 0, stream>>>(deg, off, cursor);
    k1_node_mfma<<<(N_NODES + 127) / 128, 256, 0, stream>>>(
        fn, Wn, u_src, u_dst, zb, s_src, s_dst);
    k2_edge_gemm_mfma<<<N_EDGES / 128, 256, 0, stream>>>(
        fe, We, v_e, src, dst, s_src, s_dst, cursor, ze_out, csr_src, csr_e);
    k6_aggregate<<<(N_NODES + 3) / 4, 256, 0, stream>>>(
        off, csr_src, csr_e, zb, h_out);
}